// Round 4
// baseline (395.583 us; speedup 1.0000x reference)
//
#include <hip/hip_runtime.h>
#include <math.h>

#define NTOT 32768
#define NPG  2048
#define INDIM 32
#define HID  128
#define OUTD 64
#define NPAIR 100000
#define NEG_SLOPE 0.2f
#define AST 68   // padded LDS leading stride (floats)

// ---------------------------------------------------------------------------
// prep: h = x@linW + b (LDS only) ; xl = h@gatW ; a_src = xl.attS ; a_dst
// block = 256 threads, 16 nodes
// ---------------------------------------------------------------------------
__global__ __launch_bounds__(256) void prep_kernel(
    const float* __restrict__ x, const float* __restrict__ linW,
    const float* __restrict__ linb, const float* __restrict__ gatW,
    const float* __restrict__ attS, const float* __restrict__ attD,
    float* __restrict__ xl, float* __restrict__ asrc, float* __restrict__ adst)
{
  __shared__ float xs[16][INDIM];
  __shared__ float hsm[16][HID + 1];
  __shared__ float xls[16][HID + 1];
  const int t = threadIdx.x;
  const int n0 = blockIdx.x * 16;
  for (int i = t; i < 16 * INDIM; i += 256) xs[i >> 5][i & 31] = x[(size_t)n0 * INDIM + i];
  __syncthreads();
  const int j = t & 127, half = t >> 7;
  float hacc[8];
  const float bj = linb[j];
#pragma unroll
  for (int nl = 0; nl < 8; nl++) hacc[nl] = bj;
#pragma unroll
  for (int i = 0; i < INDIM; i++) {
    const float w = linW[i * HID + j];
#pragma unroll
    for (int nl = 0; nl < 8; nl++) hacc[nl] = fmaf(xs[half * 8 + nl][i], w, hacc[nl]);
  }
#pragma unroll
  for (int nl = 0; nl < 8; nl++) hsm[half * 8 + nl][j] = hacc[nl];
  __syncthreads();
  float xacc[8];
#pragma unroll
  for (int nl = 0; nl < 8; nl++) xacc[nl] = 0.f;
  for (int k = 0; k < HID; k++) {
    const float w = gatW[k * HID + j];
#pragma unroll
    for (int nl = 0; nl < 8; nl++) xacc[nl] = fmaf(hsm[half * 8 + nl][k], w, xacc[nl]);
  }
#pragma unroll
  for (int nl = 0; nl < 8; nl++) {
    xls[half * 8 + nl][j] = xacc[nl];
    xl[(size_t)(n0 + half * 8 + nl) * HID + j] = xacc[nl];
  }
  __syncthreads();
  if (t < 16) {
    float as_ = 0.f, ad = 0.f;
    for (int k = 0; k < HID; k++) {
      const float xv = xls[t][k];
      as_ = fmaf(xv, attS[k], as_);
      ad  = fmaf(xv, attD[k], ad);
    }
    asrc[n0 + t] = as_; adst[n0 + t] = ad;
  }
}

// ---------------------------------------------------------------------------
// GAT attention with the reference's (degenerate) neighbor pattern:
//   d2 + eye*inf  =>  off-diag NaN, diag inf  =>  top_k picks lowest-index
//   NaNs: row loc -> neighbors {0..16}\{loc} first 16, then self appended.
// block = 256 threads = 2 nodes x 128 lanes
// ---------------------------------------------------------------------------
__global__ __launch_bounds__(256) void attn_kernel(
    const float* __restrict__ xl, const float* __restrict__ asrc,
    const float* __restrict__ adst, const float* __restrict__ gatb,
    float* __restrict__ gout)
{
  __shared__ int cs[2][17];
  __shared__ float al[2][17];
  const int t = threadIdx.x;
  const int nl = t >> 7, j = t & 127;
  const int n = blockIdx.x * 2 + nl;
  const int loc = n & (NPG - 1);
  const int gb = n & ~(NPG - 1);
  if (j < 17) {
    int c;
    if (j < 16) {
      const int nb = (loc < 16) ? ((j < loc) ? j : j + 1) : j;
      c = gb + nb;
    } else {
      c = n;  // self loop
    }
    cs[nl][j] = c;
    al[nl][j] = asrc[c];
  }
  __syncthreads();
  const float ad = adst[n];
  float m = -__builtin_inff();
#pragma unroll
  for (int k = 0; k < 17; k++) {
    float l = al[nl][k] + ad;
    l = (l > 0.f) ? l : NEG_SLOPE * l;
    m = fmaxf(m, l);
  }
  float w[17]; float den = 0.f;
#pragma unroll
  for (int k = 0; k < 17; k++) {
    float l = al[nl][k] + ad;
    l = (l > 0.f) ? l : NEG_SLOPE * l;
    w[k] = expf(l - m);
    den += w[k];
  }
  const float inv = 1.f / den;
  float accv = 0.f;
#pragma unroll
  for (int k = 0; k < 17; k++)
    accv = fmaf(w[k], xl[(size_t)cs[nl][k] * HID + j], accv);
  gout[(size_t)n * HID + j] = accv * inv + gatb[j];
}

// ---------------------------------------------------------------------------
// tiled GEMM: C[M,N] = act(A[M,K] @ W[K,N] + bias), all fp32, M=32768
// ---------------------------------------------------------------------------
template <int K, int N, int BN, bool RELU>
__global__ __launch_bounds__(256) void gemm_kernel(
    const float* __restrict__ A, const float* __restrict__ W,
    const float* __restrict__ bias, float* __restrict__ C)
{
  constexpr int TN = BN / 16;
  __shared__ float As[64][AST];
  __shared__ float Bs[64][BN];
  const int m0 = blockIdx.x << 6;
  const int n0 = blockIdx.y * BN;
  const int t = threadIdx.x;
  const int tr = t >> 4, tc = t & 15;
  float acc[4][TN];
#pragma unroll
  for (int i = 0; i < 4; i++)
#pragma unroll
    for (int jj = 0; jj < TN; jj++) acc[i][jj] = 0.f;

  for (int kt = 0; kt < K; kt += 64) {
    __syncthreads();
    for (int i = t; i < 64 * 16; i += 256) {
      const int r = i >> 4, k4 = (i & 15) << 2;
      const float4 v = *(const float4*)&A[(size_t)(m0 + r) * K + kt + k4];
      As[k4 + 0][r] = v.x; As[k4 + 1][r] = v.y; As[k4 + 2][r] = v.z; As[k4 + 3][r] = v.w;
    }
    for (int i = t; i < 64 * (BN / 4); i += 256) {
      const int k = i / (BN / 4), c4 = (i % (BN / 4)) << 2;
      *(float4*)&Bs[k][c4] = *(const float4*)&W[(size_t)(kt + k) * N + n0 + c4];
    }
    __syncthreads();
#pragma unroll 4
    for (int kk = 0; kk < 64; kk++) {
      const float4 a = *(const float4*)&As[kk][tr << 2];
      const float4 b0 = *(const float4*)&Bs[kk][tc << 2];
      float bv[TN];
      bv[0] = b0.x; bv[1] = b0.y; bv[2] = b0.z; bv[3] = b0.w;
      if constexpr (TN == 8) {
        const float4 b1 = *(const float4*)&Bs[kk][64 + (tc << 2)];
        bv[4] = b1.x; bv[5] = b1.y; bv[6] = b1.z; bv[7] = b1.w;
      }
      const float av[4] = {a.x, a.y, a.z, a.w};
#pragma unroll
      for (int i = 0; i < 4; i++)
#pragma unroll
        for (int jj = 0; jj < TN; jj++)
          acc[i][jj] = fmaf(av[i], bv[jj], acc[i][jj]);
    }
  }
#pragma unroll
  for (int i = 0; i < 4; i++) {
    const int r = m0 + (tr << 2) + i;
#pragma unroll
    for (int jj = 0; jj < TN; jj++) {
      const int c = n0 + ((jj < 4) ? (tc << 2) + jj : 64 + (tc << 2) + (jj - 4));
      float v = acc[i][jj] + bias[c];
      if (RELU) v = fmaxf(v, 0.f);
      C[(size_t)r * N + c] = v;
    }
  }
}

// ---------------------------------------------------------------------------
// pairs layout detection: flag=1 iff packed-int32 (some high u32 nonzero in
// the first NPAIR u64 words — safe to read in both layouts)
// ---------------------------------------------------------------------------
__global__ __launch_bounds__(256) void detect_kernel(
    const unsigned long long* __restrict__ p64, int* __restrict__ flag)
{
  __shared__ int s;
  if (threadIdx.x == 0) s = 0;
  __syncthreads();
  int loc = 0;
  for (int i = threadIdx.x; i < NPAIR; i += 256)
    loc |= ((p64[i] >> 32) != 0ull) ? 1 : 0;
  if (loc) atomicOr(&s, 1);
  __syncthreads();
  if (threadIdx.x == 0) *flag = s;
}

// ---------------------------------------------------------------------------
// final pair gather (fp32 out): [emb[pairs[:,0]], emb[pairs[:,1]]] ++ labels
// handles pairs stored as int64 (flag=0) or int32 (flag=1)
// ---------------------------------------------------------------------------
__global__ __launch_bounds__(256) void gather_kernel(
    const float* __restrict__ emb, const unsigned long long* __restrict__ p64,
    const float* __restrict__ labels, const int* __restrict__ flagp,
    float* __restrict__ out)
{
  const int i = blockIdx.x * 256 + threadIdx.x;
  const int tot = 2 * NPAIR * OUTD;
  if (i < tot) {
    const int fl = *flagp;
    const int which = i / (NPAIR * OUTD);
    const int rem = i - which * (NPAIR * OUTD);
    const int p = rem >> 6, j = rem & 63;
    const int fi = p * 2 + which;
    int node;
    if (fl) {
      const unsigned long long w = p64[fi >> 1];
      node = (int)((fi & 1) ? (w >> 32) : (w & 0xffffffffull));
    } else {
      node = (int)p64[fi];
    }
    node &= (NTOT - 1);
    out[i] = emb[(size_t)node * OUTD + j];
  } else if (i < tot + NPAIR) {
    out[i] = labels[i - tot];
  }
}

extern "C" void kernel_launch(void* const* d_in, const int* in_sizes, int n_in,
                              void* d_out, int out_size, void* d_ws, size_t ws_size,
                              hipStream_t stream)
{
  const float* x      = (const float*)d_in[0];
  const unsigned long long* pairs = (const unsigned long long*)d_in[2];
  const float* labels = (const float*)d_in[3];
  const float* linW   = (const float*)d_in[4];
  const float* linb   = (const float*)d_in[5];
  const float* gatW   = (const float*)d_in[6];
  const float* attS   = (const float*)d_in[7];
  const float* attD   = (const float*)d_in[8];
  const float* gatb   = (const float*)d_in[9];
  const float* W1     = (const float*)d_in[10];
  const float* b1     = (const float*)d_in[11];
  const float* W2     = (const float*)d_in[12];
  const float* b2     = (const float*)d_in[13];
  const float* W3     = (const float*)d_in[14];
  const float* b3     = (const float*)d_in[15];

  float* ws = (float*)d_ws;
  const size_t NT = NTOT;
  float* xl   = ws;                    // [N,128]
  float* gout = ws + NT * 128;         // [N,128]
  float* e1   = ws + NT * 256;         // [N,512]
  float* emb  = ws + NT * 768;         // [N,64]
  float* asrc = ws + NT * 832;         // [N]
  float* adst = asrc + NT;             // [N]
  int*   flag = (int*)(adst + NT);     // [1]
  float* e2   = ws;                    // [N,256] aliases xl+gout (dead by then)

  prep_kernel<<<NTOT / 16, 256, 0, stream>>>(x, linW, linb, gatW, attS, attD,
                                             xl, asrc, adst);
  attn_kernel<<<NTOT / 2, 256, 0, stream>>>(xl, asrc, adst, gatb, gout);
  gemm_kernel<128, 512, 128, true ><<<dim3(NTOT / 64, 4), 256, 0, stream>>>(gout, W1, b1, e1);
  gemm_kernel<512, 256, 128, true ><<<dim3(NTOT / 64, 2), 256, 0, stream>>>(e1, W2, b2, e2);
  gemm_kernel<256,  64,  64, false><<<dim3(NTOT / 64, 1), 256, 0, stream>>>(e2, W3, b3, emb);
  detect_kernel<<<1, 256, 0, stream>>>(pairs, flag);
  const int total = 2 * NPAIR * OUTD + NPAIR;
  gather_kernel<<<(total + 255) / 256, 256, 0, stream>>>(emb, pairs, labels, flag, (float*)d_out);
}

// Round 5
// 304.439 us; speedup vs baseline: 1.2994x; 1.2994x over previous
//
#include <hip/hip_runtime.h>
#include <math.h>

#define NTOT 32768
#define NPG  2048
#define INDIM 32
#define HID  128
#define OUTD 64
#define NPAIR 100000
#define NEG_SLOPE 0.2f
#define AST 68   // padded LDS leading stride (floats)

// ---------------------------------------------------------------------------
// prep: h = x@linW + b (LDS only) ; xl = h@gatW ; a_src = xl.attS ; a_dst
// block = 256 threads, 16 nodes
// ---------------------------------------------------------------------------
__global__ __launch_bounds__(256) void prep_kernel(
    const float* __restrict__ x, const float* __restrict__ linW,
    const float* __restrict__ linb, const float* __restrict__ gatW,
    const float* __restrict__ attS, const float* __restrict__ attD,
    float* __restrict__ xl, float* __restrict__ asrc, float* __restrict__ adst)
{
  __shared__ float xs[16][INDIM];
  __shared__ float hsm[16][HID + 1];
  __shared__ float xls[16][HID + 1];
  const int t = threadIdx.x;
  const int n0 = blockIdx.x * 16;
  for (int i = t; i < 16 * INDIM; i += 256) xs[i >> 5][i & 31] = x[(size_t)n0 * INDIM + i];
  __syncthreads();
  const int j = t & 127, half = t >> 7;
  float hacc[8];
  const float bj = linb[j];
#pragma unroll
  for (int nl = 0; nl < 8; nl++) hacc[nl] = bj;
#pragma unroll
  for (int i = 0; i < INDIM; i++) {
    const float w = linW[i * HID + j];
#pragma unroll
    for (int nl = 0; nl < 8; nl++) hacc[nl] = fmaf(xs[half * 8 + nl][i], w, hacc[nl]);
  }
#pragma unroll
  for (int nl = 0; nl < 8; nl++) hsm[half * 8 + nl][j] = hacc[nl];
  __syncthreads();
  float xacc[8];
#pragma unroll
  for (int nl = 0; nl < 8; nl++) xacc[nl] = 0.f;
  for (int k = 0; k < HID; k++) {
    const float w = gatW[k * HID + j];
#pragma unroll
    for (int nl = 0; nl < 8; nl++) xacc[nl] = fmaf(hsm[half * 8 + nl][k], w, xacc[nl]);
  }
#pragma unroll
  for (int nl = 0; nl < 8; nl++) {
    xls[half * 8 + nl][j] = xacc[nl];
    xl[(size_t)(n0 + half * 8 + nl) * HID + j] = xacc[nl];
  }
  __syncthreads();
  if (t < 16) {
    float as_ = 0.f, ad = 0.f;
    for (int k = 0; k < HID; k++) {
      const float xv = xls[t][k];
      as_ = fmaf(xv, attS[k], as_);
      ad  = fmaf(xv, attD[k], ad);
    }
    asrc[n0 + t] = as_; adst[n0 + t] = ad;
  }
}

// ---------------------------------------------------------------------------
// GAT attention with the reference's (degenerate) neighbor pattern:
//   d2 + eye*inf  =>  off-diag NaN, diag inf  =>  top_k picks lowest-index
//   NaNs: row loc -> neighbors {0..16}\{loc} first 16, then self appended.
// block = 256 threads = 2 nodes x 128 lanes
// ---------------------------------------------------------------------------
__global__ __launch_bounds__(256) void attn_kernel(
    const float* __restrict__ xl, const float* __restrict__ asrc,
    const float* __restrict__ adst, const float* __restrict__ gatb,
    float* __restrict__ gout)
{
  __shared__ int cs[2][17];
  __shared__ float al[2][17];
  const int t = threadIdx.x;
  const int nl = t >> 7, j = t & 127;
  const int n = blockIdx.x * 2 + nl;
  const int loc = n & (NPG - 1);
  const int gb = n & ~(NPG - 1);
  if (j < 17) {
    int c;
    if (j < 16) {
      const int nb = (loc < 16) ? ((j < loc) ? j : j + 1) : j;
      c = gb + nb;
    } else {
      c = n;  // self loop
    }
    cs[nl][j] = c;
    al[nl][j] = asrc[c];
  }
  __syncthreads();
  const float ad = adst[n];
  float m = -__builtin_inff();
#pragma unroll
  for (int k = 0; k < 17; k++) {
    float l = al[nl][k] + ad;
    l = (l > 0.f) ? l : NEG_SLOPE * l;
    m = fmaxf(m, l);
  }
  float w[17]; float den = 0.f;
#pragma unroll
  for (int k = 0; k < 17; k++) {
    float l = al[nl][k] + ad;
    l = (l > 0.f) ? l : NEG_SLOPE * l;
    w[k] = expf(l - m);
    den += w[k];
  }
  const float inv = 1.f / den;
  float accv = 0.f;
#pragma unroll
  for (int k = 0; k < 17; k++)
    accv = fmaf(w[k], xl[(size_t)cs[nl][k] * HID + j], accv);
  gout[(size_t)n * HID + j] = accv * inv + gatb[j];
}

// ---------------------------------------------------------------------------
// tiled GEMM: C[M,N] = act(A[M,K] @ W[K,N] + bias), all fp32, M=32768
// ---------------------------------------------------------------------------
template <int K, int N, int BN, bool RELU>
__global__ __launch_bounds__(256) void gemm_kernel(
    const float* __restrict__ A, const float* __restrict__ W,
    const float* __restrict__ bias, float* __restrict__ C)
{
  constexpr int TN = BN / 16;
  __shared__ float As[64][AST];
  __shared__ float Bs[64][BN];
  const int m0 = blockIdx.x << 6;
  const int n0 = blockIdx.y * BN;
  const int t = threadIdx.x;
  const int tr = t >> 4, tc = t & 15;
  float acc[4][TN];
#pragma unroll
  for (int i = 0; i < 4; i++)
#pragma unroll
    for (int jj = 0; jj < TN; jj++) acc[i][jj] = 0.f;

  for (int kt = 0; kt < K; kt += 64) {
    __syncthreads();
    for (int i = t; i < 64 * 16; i += 256) {
      const int r = i >> 4, k4 = (i & 15) << 2;
      const float4 v = *(const float4*)&A[(size_t)(m0 + r) * K + kt + k4];
      As[k4 + 0][r] = v.x; As[k4 + 1][r] = v.y; As[k4 + 2][r] = v.z; As[k4 + 3][r] = v.w;
    }
    for (int i = t; i < 64 * (BN / 4); i += 256) {
      const int k = i / (BN / 4), c4 = (i % (BN / 4)) << 2;
      *(float4*)&Bs[k][c4] = *(const float4*)&W[(size_t)(kt + k) * N + n0 + c4];
    }
    __syncthreads();
#pragma unroll 4
    for (int kk = 0; kk < 64; kk++) {
      const float4 a = *(const float4*)&As[kk][tr << 2];
      const float4 b0 = *(const float4*)&Bs[kk][tc << 2];
      float bv[TN];
      bv[0] = b0.x; bv[1] = b0.y; bv[2] = b0.z; bv[3] = b0.w;
      if constexpr (TN == 8) {
        const float4 b1 = *(const float4*)&Bs[kk][64 + (tc << 2)];
        bv[4] = b1.x; bv[5] = b1.y; bv[6] = b1.z; bv[7] = b1.w;
      }
      const float av[4] = {a.x, a.y, a.z, a.w};
#pragma unroll
      for (int i = 0; i < 4; i++)
#pragma unroll
        for (int jj = 0; jj < TN; jj++)
          acc[i][jj] = fmaf(av[i], bv[jj], acc[i][jj]);
    }
  }
#pragma unroll
  for (int i = 0; i < 4; i++) {
    const int r = m0 + (tr << 2) + i;
#pragma unroll
    for (int jj = 0; jj < TN; jj++) {
      const int c = n0 + ((jj < 4) ? (tc << 2) + jj : 64 + (tc << 2) + (jj - 4));
      float v = acc[i][jj] + bias[c];
      if (RELU) v = fmaxf(v, 0.f);
      C[(size_t)r * N + c] = v;
    }
  }
}

// ---------------------------------------------------------------------------
// pairs layout detection, parallel version.
// init: flag=0. detect: 256 blocks grid-stride; per-block LDS reduce; one
// device atomicOr per block that saw a nonzero high u32 (=> packed-int32).
// ---------------------------------------------------------------------------
__global__ void init_flag_kernel(int* __restrict__ flag) { *flag = 0; }

__global__ __launch_bounds__(256) void detect_kernel(
    const unsigned long long* __restrict__ p64, int* __restrict__ flag)
{
  __shared__ int s;
  if (threadIdx.x == 0) s = 0;
  __syncthreads();
  int loc = 0;
  for (int i = blockIdx.x * 256 + threadIdx.x; i < NPAIR; i += 256 * 256)
    loc |= ((p64[i] >> 32) != 0ull) ? 1 : 0;
  if (loc) atomicOr(&s, 1);
  __syncthreads();
  if (threadIdx.x == 0 && s) atomicOr(flag, 1);
}

// ---------------------------------------------------------------------------
// final pair gather (fp32 out): [emb[pairs[:,0]], emb[pairs[:,1]]] ++ labels
// handles pairs stored as int64 (flag=0) or int32 (flag=1)
// ---------------------------------------------------------------------------
__global__ __launch_bounds__(256) void gather_kernel(
    const float* __restrict__ emb, const unsigned long long* __restrict__ p64,
    const float* __restrict__ labels, const int* __restrict__ flagp,
    float* __restrict__ out)
{
  const int i = blockIdx.x * 256 + threadIdx.x;
  const int tot = 2 * NPAIR * OUTD;
  if (i < tot) {
    const int fl = *flagp;
    const int which = i / (NPAIR * OUTD);
    const int rem = i - which * (NPAIR * OUTD);
    const int p = rem >> 6, j = rem & 63;
    const int fi = p * 2 + which;
    int node;
    if (fl) {
      const unsigned long long w = p64[fi >> 1];
      node = (int)((fi & 1) ? (w >> 32) : (w & 0xffffffffull));
    } else {
      node = (int)p64[fi];
    }
    node &= (NTOT - 1);
    out[i] = emb[(size_t)node * OUTD + j];
  } else if (i < tot + NPAIR) {
    out[i] = labels[i - tot];
  }
}

extern "C" void kernel_launch(void* const* d_in, const int* in_sizes, int n_in,
                              void* d_out, int out_size, void* d_ws, size_t ws_size,
                              hipStream_t stream)
{
  const float* x      = (const float*)d_in[0];
  const unsigned long long* pairs = (const unsigned long long*)d_in[2];
  const float* labels = (const float*)d_in[3];
  const float* linW   = (const float*)d_in[4];
  const float* linb   = (const float*)d_in[5];
  const float* gatW   = (const float*)d_in[6];
  const float* attS   = (const float*)d_in[7];
  const float* attD   = (const float*)d_in[8];
  const float* gatb   = (const float*)d_in[9];
  const float* W1     = (const float*)d_in[10];
  const float* b1     = (const float*)d_in[11];
  const float* W2     = (const float*)d_in[12];
  const float* b2     = (const float*)d_in[13];
  const float* W3     = (const float*)d_in[14];
  const float* b3     = (const float*)d_in[15];

  float* ws = (float*)d_ws;
  const size_t NT = NTOT;
  float* xl   = ws;                    // [N,128]
  float* gout = ws + NT * 128;         // [N,128]
  float* e1   = ws + NT * 256;         // [N,512]
  float* emb  = ws + NT * 768;         // [N,64]
  float* asrc = ws + NT * 832;         // [N]
  float* adst = asrc + NT;             // [N]
  int*   flag = (int*)(adst + NT);     // [1]
  float* e2   = ws;                    // [N,256] aliases xl+gout (dead by then)

  init_flag_kernel<<<1, 1, 0, stream>>>(flag);
  detect_kernel<<<256, 256, 0, stream>>>(pairs, flag);
  prep_kernel<<<NTOT / 16, 256, 0, stream>>>(x, linW, linb, gatW, attS, attD,
                                             xl, asrc, adst);
  attn_kernel<<<NTOT / 2, 256, 0, stream>>>(xl, asrc, adst, gatb, gout);
  gemm_kernel<128, 512, 128, true ><<<dim3(NTOT / 64, 4), 256, 0, stream>>>(gout, W1, b1, e1);
  gemm_kernel<512, 256, 128, true ><<<dim3(NTOT / 64, 2), 256, 0, stream>>>(e1, W2, b2, e2);
  gemm_kernel<256,  64,  64, false><<<dim3(NTOT / 64, 1), 256, 0, stream>>>(e2, W3, b3, emb);
  const int total = 2 * NPAIR * OUTD + NPAIR;
  gather_kernel<<<(total + 255) / 256, 256, 0, stream>>>(emb, pairs, labels, flag, (float*)d_out);
}

// Round 6
// 205.498 us; speedup vs baseline: 1.9250x; 1.4815x over previous
//
#include <hip/hip_runtime.h>
#include <math.h>

#define NTOT 32768
#define NPG  2048
#define INDIM 32
#define HID  128
#define OUTD 64
#define NPAIR 100000
#define NEG_SLOPE 0.2f

typedef short bf16x8 __attribute__((ext_vector_type(8)));
typedef float f32x4 __attribute__((ext_vector_type(4)));

static __device__ __forceinline__ float b2f(ushort u) {
  return __uint_as_float(((unsigned)u) << 16);
}
static __device__ __forceinline__ ushort f2b(float f) {
  unsigned u = __float_as_uint(f);
  unsigned r = (u + 0x7fffu + ((u >> 16) & 1u)) >> 16;   // RNE
  return (ushort)r;
}

// ---------------------------------------------------------------------------
// prep: h = x@linW + b (LDS only) ; xl = h@gatW ; a_src = xl.attS ; a_dst
// block = 256 threads, 16 nodes
// ---------------------------------------------------------------------------
__global__ __launch_bounds__(256) void prep_kernel(
    const float* __restrict__ x, const float* __restrict__ linW,
    const float* __restrict__ linb, const float* __restrict__ gatW,
    const float* __restrict__ attS, const float* __restrict__ attD,
    float* __restrict__ xl, float* __restrict__ asrc, float* __restrict__ adst)
{
  __shared__ float xs[16][INDIM];
  __shared__ float hsm[16][HID + 1];
  __shared__ float xls[16][HID + 1];
  const int t = threadIdx.x;
  const int n0 = blockIdx.x * 16;
  for (int i = t; i < 16 * INDIM; i += 256) xs[i >> 5][i & 31] = x[(size_t)n0 * INDIM + i];
  __syncthreads();
  const int j = t & 127, half = t >> 7;
  float hacc[8];
  const float bj = linb[j];
#pragma unroll
  for (int nl = 0; nl < 8; nl++) hacc[nl] = bj;
#pragma unroll
  for (int i = 0; i < INDIM; i++) {
    const float w = linW[i * HID + j];
#pragma unroll
    for (int nl = 0; nl < 8; nl++) hacc[nl] = fmaf(xs[half * 8 + nl][i], w, hacc[nl]);
  }
#pragma unroll
  for (int nl = 0; nl < 8; nl++) hsm[half * 8 + nl][j] = hacc[nl];
  __syncthreads();
  float xacc[8];
#pragma unroll
  for (int nl = 0; nl < 8; nl++) xacc[nl] = 0.f;
  for (int k = 0; k < HID; k++) {
    const float w = gatW[k * HID + j];
#pragma unroll
    for (int nl = 0; nl < 8; nl++) xacc[nl] = fmaf(hsm[half * 8 + nl][k], w, xacc[nl]);
  }
#pragma unroll
  for (int nl = 0; nl < 8; nl++) {
    xls[half * 8 + nl][j] = xacc[nl];
    xl[(size_t)(n0 + half * 8 + nl) * HID + j] = xacc[nl];
  }
  __syncthreads();
  if (t < 16) {
    float as_ = 0.f, ad = 0.f;
    for (int k = 0; k < HID; k++) {
      const float xv = xls[t][k];
      as_ = fmaf(xv, attS[k], as_);
      ad  = fmaf(xv, attD[k], ad);
    }
    asrc[n0 + t] = as_; adst[n0 + t] = ad;
  }
}

// ---------------------------------------------------------------------------
// GAT attention (reference's degenerate neighbor pattern); emits hi/lo bf16
// block = 256 threads = 2 nodes x 128 lanes
// ---------------------------------------------------------------------------
__global__ __launch_bounds__(256) void attn_kernel(
    const float* __restrict__ xl, const float* __restrict__ asrc,
    const float* __restrict__ adst, const float* __restrict__ gatb,
    ushort* __restrict__ ghi, ushort* __restrict__ glo)
{
  __shared__ int cs[2][17];
  __shared__ float al[2][17];
  const int t = threadIdx.x;
  const int nl = t >> 7, j = t & 127;
  const int n = blockIdx.x * 2 + nl;
  const int loc = n & (NPG - 1);
  const int gb = n & ~(NPG - 1);
  if (j < 17) {
    int c;
    if (j < 16) {
      const int nb = (loc < 16) ? ((j < loc) ? j : j + 1) : j;
      c = gb + nb;
    } else {
      c = n;  // self loop
    }
    cs[nl][j] = c;
    al[nl][j] = asrc[c];
  }
  __syncthreads();
  const float ad = adst[n];
  float m = -__builtin_inff();
#pragma unroll
  for (int k = 0; k < 17; k++) {
    float l = al[nl][k] + ad;
    l = (l > 0.f) ? l : NEG_SLOPE * l;
    m = fmaxf(m, l);
  }
  float w[17]; float den = 0.f;
#pragma unroll
  for (int k = 0; k < 17; k++) {
    float l = al[nl][k] + ad;
    l = (l > 0.f) ? l : NEG_SLOPE * l;
    w[k] = expf(l - m);
    den += w[k];
  }
  const float inv = 1.f / den;
  float accv = 0.f;
#pragma unroll
  for (int k = 0; k < 17; k++)
    accv = fmaf(w[k], xl[(size_t)cs[nl][k] * HID + j], accv);
  const float v = accv * inv + gatb[j];
  const ushort hi = f2b(v);
  ghi[(size_t)n * HID + j] = hi;
  glo[(size_t)n * HID + j] = f2b(v - b2f(hi));
}

// ---------------------------------------------------------------------------
// weight convert: W[K][N] fp32 -> Wt_hi/Wt_lo [N][K] bf16 (split, transposed)
// ---------------------------------------------------------------------------
__global__ __launch_bounds__(256) void convw_kernel(
    const float* __restrict__ W, int Kd, int Nd,
    ushort* __restrict__ Whi, ushort* __restrict__ Wlo)
{
  const int i = blockIdx.x * 256 + threadIdx.x;
  if (i < Kd * Nd) {
    const int k = i / Nd, n = i - k * Nd;
    const float v = W[i];
    const ushort hi = f2b(v);
    Whi[(size_t)n * Kd + k] = hi;
    Wlo[(size_t)n * Kd + k] = f2b(v - b2f(hi));
  }
}

// ---------------------------------------------------------------------------
// MFMA split-bf16 GEMM: C[M,N] = act(A @ W + bias), A = Ahi+Alo [M][K] bf16,
// W given transposed+split: Wt_hi/lo [N][K]. 3-term: ahi*bhi+ahi*blo+alo*bhi.
// Block: 128 x BN tile, BK=32, 4 waves (2x2), wave tile 64 x BN/2.
// ---------------------------------------------------------------------------
template <int K, int N, int BN, bool RELU, bool SPLIT_OUT>
__global__ __launch_bounds__(256) void mgemm_kernel(
    const ushort* __restrict__ Ahi, const ushort* __restrict__ Alo,
    const ushort* __restrict__ Whi, const ushort* __restrict__ Wlo,
    const float* __restrict__ bias, float* __restrict__ C,
    ushort* __restrict__ Chi, ushort* __restrict__ Clo)
{
  constexpr int BK = 32;
  constexpr int LDA = BK + 8;           // 40 bf16 = 80B row stride (16B-aligned, 2-way banks)
  constexpr int NC = BN / 32;           // 16x16 col-frags per wave
  __shared__ __align__(16) ushort sA[2][128][LDA];
  __shared__ __align__(16) ushort sB[2][BN][LDA];
  const int m0 = blockIdx.x * 128;
  const int n0 = blockIdx.y * BN;
  const int t = threadIdx.x;
  const int wave = t >> 6, lane = t & 63;
  const int wr = (wave >> 1) * 64;
  const int wc = (wave & 1) * (BN / 2);
  const int frow = lane & 15;
  const int kb = (lane >> 4) * 8;

  f32x4 acc[4][NC];
#pragma unroll
  for (int fr = 0; fr < 4; fr++)
#pragma unroll
    for (int fc = 0; fc < NC; fc++) acc[fr][fc] = (f32x4){0.f, 0.f, 0.f, 0.f};

  for (int kt = 0; kt < K; kt += BK) {
    __syncthreads();   // previous tile's frag reads done
#pragma unroll
    for (int c = t; c < 512; c += 256) {          // A: 128 rows x 32k, 16B chunks
      const int r = c >> 2, ko = (c & 3) << 3;
      const size_t g = (size_t)(m0 + r) * K + kt + ko;
      *(uint4*)&sA[0][r][ko] = *(const uint4*)&Ahi[g];
      *(uint4*)&sA[1][r][ko] = *(const uint4*)&Alo[g];
    }
    for (int c = t; c < BN * 4; c += 256) {       // B: BN rows x 32k
      const int r = c >> 2, ko = (c & 3) << 3;
      const size_t g = (size_t)(n0 + r) * K + kt + ko;
      *(uint4*)&sB[0][r][ko] = *(const uint4*)&Whi[g];
      *(uint4*)&sB[1][r][ko] = *(const uint4*)&Wlo[g];
    }
    __syncthreads();

    bf16x8 afh[4], afl[4], bfh[NC], bfl[NC];
#pragma unroll
    for (int fr = 0; fr < 4; fr++) {
      const int r = wr + fr * 16 + frow;
      afh[fr] = *(const bf16x8*)&sA[0][r][kb];
      afl[fr] = *(const bf16x8*)&sA[1][r][kb];
    }
#pragma unroll
    for (int fc = 0; fc < NC; fc++) {
      const int r = wc + fc * 16 + frow;
      bfh[fc] = *(const bf16x8*)&sB[0][r][kb];
      bfl[fc] = *(const bf16x8*)&sB[1][r][kb];
    }
#pragma unroll
    for (int fr = 0; fr < 4; fr++)
#pragma unroll
      for (int fc = 0; fc < NC; fc++) {
        acc[fr][fc] = __builtin_amdgcn_mfma_f32_16x16x32_bf16(afh[fr], bfh[fc], acc[fr][fc], 0, 0, 0);
        acc[fr][fc] = __builtin_amdgcn_mfma_f32_16x16x32_bf16(afh[fr], bfl[fc], acc[fr][fc], 0, 0, 0);
        acc[fr][fc] = __builtin_amdgcn_mfma_f32_16x16x32_bf16(afl[fr], bfh[fc], acc[fr][fc], 0, 0, 0);
      }
  }

  const int rq = (lane >> 4) * 4;
#pragma unroll
  for (int fr = 0; fr < 4; fr++)
#pragma unroll
    for (int fc = 0; fc < NC; fc++)
#pragma unroll
      for (int j = 0; j < 4; j++) {
        const int row = m0 + wr + fr * 16 + rq + j;
        const int col = n0 + wc + fc * 16 + frow;
        float v = acc[fr][fc][j] + bias[col];
        if (RELU) v = fmaxf(v, 0.f);
        if constexpr (SPLIT_OUT) {
          const ushort hi = f2b(v);
          Chi[(size_t)row * N + col] = hi;
          Clo[(size_t)row * N + col] = f2b(v - b2f(hi));
        } else {
          C[(size_t)row * N + col] = v;
        }
      }
}

// ---------------------------------------------------------------------------
// pairs layout detection (parallel) + init
// ---------------------------------------------------------------------------
__global__ void init_flag_kernel(int* __restrict__ flag) { *flag = 0; }

__global__ __launch_bounds__(256) void detect_kernel(
    const unsigned long long* __restrict__ p64, int* __restrict__ flag)
{
  __shared__ int s;
  if (threadIdx.x == 0) s = 0;
  __syncthreads();
  int loc = 0;
  for (int i = blockIdx.x * 256 + threadIdx.x; i < NPAIR; i += 256 * 256)
    loc |= ((p64[i] >> 32) != 0ull) ? 1 : 0;
  if (loc) atomicOr(&s, 1);
  __syncthreads();
  if (threadIdx.x == 0 && s) atomicOr(flag, 1);
}

// ---------------------------------------------------------------------------
// final pair gather (fp32 out): [emb[pairs[:,0]], emb[pairs[:,1]]] ++ labels
// ---------------------------------------------------------------------------
__global__ __launch_bounds__(256) void gather_kernel(
    const float* __restrict__ emb, const unsigned long long* __restrict__ p64,
    const float* __restrict__ labels, const int* __restrict__ flagp,
    float* __restrict__ out)
{
  const int i = blockIdx.x * 256 + threadIdx.x;
  const int tot = 2 * NPAIR * OUTD;
  if (i < tot) {
    const int fl = *flagp;
    const int which = i / (NPAIR * OUTD);
    const int rem = i - which * (NPAIR * OUTD);
    const int p = rem >> 6, j = rem & 63;
    const int fi = p * 2 + which;
    int node;
    if (fl) {
      const unsigned long long w = p64[fi >> 1];
      node = (int)((fi & 1) ? (w >> 32) : (w & 0xffffffffull));
    } else {
      node = (int)p64[fi];
    }
    node &= (NTOT - 1);
    out[i] = emb[(size_t)node * OUTD + j];
  } else if (i < tot + NPAIR) {
    out[i] = labels[i - tot];
  }
}

extern "C" void kernel_launch(void* const* d_in, const int* in_sizes, int n_in,
                              void* d_out, int out_size, void* d_ws, size_t ws_size,
                              hipStream_t stream)
{
  const float* x      = (const float*)d_in[0];
  const unsigned long long* pairs = (const unsigned long long*)d_in[2];
  const float* labels = (const float*)d_in[3];
  const float* linW   = (const float*)d_in[4];
  const float* linb   = (const float*)d_in[5];
  const float* gatW   = (const float*)d_in[6];
  const float* attS   = (const float*)d_in[7];
  const float* attD   = (const float*)d_in[8];
  const float* gatb   = (const float*)d_in[9];
  const float* W1     = (const float*)d_in[10];
  const float* b1     = (const float*)d_in[11];
  const float* W2     = (const float*)d_in[12];
  const float* b2     = (const float*)d_in[13];
  const float* W3     = (const float*)d_in[14];
  const float* b3     = (const float*)d_in[15];

  float* ws = (float*)d_ws;
  const size_t NT = NTOT;
  // float-offset layout (with overlays; serial stream ordering makes them safe):
  float*  xl   = ws;                         // [0,128)   dead after attn
  ushort* e1hi = (ushort*)(ws);              // [0,256)   overlays xl (gemm1 output)
  ushort* e1lo = (ushort*)(ws + NT * 256);   // [256,512)
  ushort* ghi  = (ushort*)(ws + NT * 512);   // [512,576) dead after gemm1
  ushort* glo  = (ushort*)(ws + NT * 576);   // [576,640) dead after gemm1
  ushort* e2hi = (ushort*)(ws + NT * 512);   // [512,640) overlays ghi/glo
  ushort* e2lo = (ushort*)(ws + NT * 640);   // [640,768)
  float*  emb  = ws + NT * 768;              // [768,832)
  float*  asrc = ws + NT * 832;              // [832,833)
  float*  adst = ws + NT * 833;              // [833,834)
  ushort* wt1hi = (ushort*)(ws + NT * 834);
  ushort* wt1lo = wt1hi + 512 * 128;
  ushort* wt2hi = wt1lo + 512 * 128;
  ushort* wt2lo = wt2hi + 512 * 256;
  ushort* wt3hi = wt2lo + 512 * 256;
  ushort* wt3lo = wt3hi + 256 * 64;
  int*    flag  = (int*)(wt3lo + 256 * 64);

  init_flag_kernel<<<1, 1, 0, stream>>>(flag);
  detect_kernel<<<256, 256, 0, stream>>>(pairs, flag);
  convw_kernel<<<(128 * 512 + 255) / 256, 256, 0, stream>>>(W1, 128, 512, wt1hi, wt1lo);
  convw_kernel<<<(512 * 256 + 255) / 256, 256, 0, stream>>>(W2, 512, 256, wt2hi, wt2lo);
  convw_kernel<<<(256 * 64 + 255) / 256, 256, 0, stream>>>(W3, 256, 64, wt3hi, wt3lo);
  prep_kernel<<<NTOT / 16, 256, 0, stream>>>(x, linW, linb, gatW, attS, attD,
                                             xl, asrc, adst);
  attn_kernel<<<NTOT / 2, 256, 0, stream>>>(xl, asrc, adst, gatb, ghi, glo);
  mgemm_kernel<128, 512, 128, true,  true ><<<dim3(NTOT / 128, 4), 256, 0, stream>>>(
      ghi, glo, wt1hi, wt1lo, b1, nullptr, e1hi, e1lo);
  mgemm_kernel<512, 256, 128, true,  true ><<<dim3(NTOT / 128, 2), 256, 0, stream>>>(
      e1hi, e1lo, wt2hi, wt2lo, b2, nullptr, e2hi, e2lo);
  mgemm_kernel<256,  64,  64, false, false><<<dim3(NTOT / 128, 1), 256, 0, stream>>>(
      e2hi, e2lo, wt3hi, wt3lo, b3, emb, nullptr, nullptr);
  const int total = 2 * NPAIR * OUTD + NPAIR;
  gather_kernel<<<(total + 255) / 256, 256, 0, stream>>>(emb, pairs, labels, flag, (float*)d_out);
}

// Round 7
// 190.837 us; speedup vs baseline: 2.0729x; 1.0768x over previous
//
#include <hip/hip_runtime.h>
#include <math.h>

#define NTOT 32768
#define NPG  2048
#define INDIM 32
#define HID  128
#define OUTD 64
#define NPAIR 100000
#define NEG_SLOPE 0.2f

typedef short bf16x8 __attribute__((ext_vector_type(8)));
typedef float f32x4 __attribute__((ext_vector_type(4)));

static __device__ __forceinline__ float b2f(ushort u) {
  return __uint_as_float(((unsigned)u) << 16);
}
static __device__ __forceinline__ ushort f2b(float f) {
  unsigned u = __float_as_uint(f);
  unsigned r = (u + 0x7fffu + ((u >> 16) & 1u)) >> 16;   // RNE
  return (ushort)r;
}
// chunk-swizzle: permute 8-bf16 (16B) chunks within each aligned 64-col group
// by row&7.  Involution: applying twice restores.  Consumers read LDS with the
// same XOR, so producer-side global layout + linear global_load_lds staging +
// XOR'd ds_read compose correctly (both-sides rule).
static __device__ __forceinline__ int swz_col(int row, int col) {
  return (col & ~63) | ((((col >> 3) ^ row) & 7) << 3) | (col & 7);
}

// ---------------------------------------------------------------------------
// prep: h = x@linW + b (LDS only) ; xl = h@gatW ; a_src = xl.attS ; a_dst
// ---------------------------------------------------------------------------
__global__ __launch_bounds__(256) void prep_kernel(
    const float* __restrict__ x, const float* __restrict__ linW,
    const float* __restrict__ linb, const float* __restrict__ gatW,
    const float* __restrict__ attS, const float* __restrict__ attD,
    float* __restrict__ xl, float* __restrict__ asrc, float* __restrict__ adst)
{
  __shared__ float xs[16][INDIM];
  __shared__ float hsm[16][HID + 1];
  __shared__ float xls[16][HID + 1];
  const int t = threadIdx.x;
  const int n0 = blockIdx.x * 16;
  for (int i = t; i < 16 * INDIM; i += 256) xs[i >> 5][i & 31] = x[(size_t)n0 * INDIM + i];
  __syncthreads();
  const int j = t & 127, half = t >> 7;
  float hacc[8];
  const float bj = linb[j];
#pragma unroll
  for (int nl = 0; nl < 8; nl++) hacc[nl] = bj;
#pragma unroll
  for (int i = 0; i < INDIM; i++) {
    const float w = linW[i * HID + j];
#pragma unroll
    for (int nl = 0; nl < 8; nl++) hacc[nl] = fmaf(xs[half * 8 + nl][i], w, hacc[nl]);
  }
#pragma unroll
  for (int nl = 0; nl < 8; nl++) hsm[half * 8 + nl][j] = hacc[nl];
  __syncthreads();
  float xacc[8];
#pragma unroll
  for (int nl = 0; nl < 8; nl++) xacc[nl] = 0.f;
  for (int k = 0; k < HID; k++) {
    const float w = gatW[k * HID + j];
#pragma unroll
    for (int nl = 0; nl < 8; nl++) xacc[nl] = fmaf(hsm[half * 8 + nl][k], w, xacc[nl]);
  }
#pragma unroll
  for (int nl = 0; nl < 8; nl++) {
    xls[half * 8 + nl][j] = xacc[nl];
    xl[(size_t)(n0 + half * 8 + nl) * HID + j] = xacc[nl];
  }
  __syncthreads();
  if (t < 16) {
    float as_ = 0.f, ad = 0.f;
    for (int k = 0; k < HID; k++) {
      const float xv = xls[t][k];
      as_ = fmaf(xv, attS[k], as_);
      ad  = fmaf(xv, attD[k], ad);
    }
    asrc[n0 + t] = as_; adst[n0 + t] = ad;
  }
}

// ---------------------------------------------------------------------------
// GAT attention (reference's degenerate neighbor pattern); emits hi/lo bf16
// in chunk-swizzled global layout for the MFMA GEMM consumer.
// ---------------------------------------------------------------------------
__global__ __launch_bounds__(256) void attn_kernel(
    const float* __restrict__ xl, const float* __restrict__ asrc,
    const float* __restrict__ adst, const float* __restrict__ gatb,
    ushort* __restrict__ ghi, ushort* __restrict__ glo)
{
  __shared__ int cs[2][17];
  __shared__ float al[2][17];
  const int t = threadIdx.x;
  const int nl = t >> 7, j = t & 127;
  const int n = blockIdx.x * 2 + nl;
  const int loc = n & (NPG - 1);
  const int gb = n & ~(NPG - 1);
  if (j < 17) {
    int c;
    if (j < 16) {
      const int nb = (loc < 16) ? ((j < loc) ? j : j + 1) : j;
      c = gb + nb;
    } else {
      c = n;  // self loop
    }
    cs[nl][j] = c;
    al[nl][j] = asrc[c];
  }
  __syncthreads();
  const float ad = adst[n];
  float m = -__builtin_inff();
#pragma unroll
  for (int k = 0; k < 17; k++) {
    float l = al[nl][k] + ad;
    l = (l > 0.f) ? l : NEG_SLOPE * l;
    m = fmaxf(m, l);
  }
  float w[17]; float den = 0.f;
#pragma unroll
  for (int k = 0; k < 17; k++) {
    float l = al[nl][k] + ad;
    l = (l > 0.f) ? l : NEG_SLOPE * l;
    w[k] = expf(l - m);
    den += w[k];
  }
  const float inv = 1.f / den;
  float accv = 0.f;
#pragma unroll
  for (int k = 0; k < 17; k++)
    accv = fmaf(w[k], xl[(size_t)cs[nl][k] * HID + j], accv);
  const float v = accv * inv + gatb[j];
  const ushort hi = f2b(v);
  const int jc = swz_col(n, j);
  ghi[(size_t)n * HID + jc] = hi;
  glo[(size_t)n * HID + jc] = f2b(v - b2f(hi));
}

// ---------------------------------------------------------------------------
// weight convert: W[K][N] fp32 -> Wt_hi/lo [N][K] bf16, transposed + swizzled
// ---------------------------------------------------------------------------
__global__ __launch_bounds__(256) void convw_kernel(
    const float* __restrict__ W, int Kd, int Nd,
    ushort* __restrict__ Whi, ushort* __restrict__ Wlo)
{
  const int i = blockIdx.x * 256 + threadIdx.x;
  if (i < Kd * Nd) {
    const int k = i / Nd, n = i - k * Nd;
    const float v = W[i];
    const ushort hi = f2b(v);
    const int kc = swz_col(n, k);
    Whi[(size_t)n * Kd + kc] = hi;
    Wlo[(size_t)n * Kd + kc] = f2b(v - b2f(hi));
  }
}

// ---------------------------------------------------------------------------
// MFMA split-bf16 GEMM (m97-style): C = act(A@W + bias).
// A = Ahi+Alo [M][K] bf16 swizzled; W transposed+split+swizzled [N][K].
// BM=128, BK=64, 4 waves 2x2 (wave 64 x BN/2).  Staging via
// global_load_lds dwordx4 into linear LDS; ds_read with chunk-XOR.
// ---------------------------------------------------------------------------
template <int K, int N, int BN, bool RELU, bool SPLIT_OUT>
__global__ __launch_bounds__(256) void mgemm_kernel(
    const ushort* __restrict__ Ahi, const ushort* __restrict__ Alo,
    const ushort* __restrict__ Whi, const ushort* __restrict__ Wlo,
    const float* __restrict__ bias, float* __restrict__ C,
    ushort* __restrict__ Chi, ushort* __restrict__ Clo)
{
  constexpr int NC = BN / 32;              // 16-col frags per wave
  constexpr int ABYTES = 128 * 128;        // 128 rows x 64 bf16 x 2B
  constexpr int BBYTES = BN * 128;
  extern __shared__ __align__(16) char lds[];
  char* Ah = lds;
  char* Al = lds + ABYTES;
  char* Bh = lds + 2 * ABYTES;
  char* Bl = lds + 2 * ABYTES + BBYTES;

  const int m0 = blockIdx.x * 128;
  const int n0 = blockIdx.y * BN;
  const int t = threadIdx.x;
  const int wv = t >> 6, lane = t & 63;
  const int frow = lane & 15, kq = lane >> 4;
  const int wr = (wv >> 1) * 64;
  const int wc = (wv & 1) * (BN / 2);
  const int srow = t >> 3, sch = t & 7;    // staging: 32 rows x 8 chunks per call

  f32x4 acc[4][NC];
#pragma unroll
  for (int fr = 0; fr < 4; fr++)
#pragma unroll
    for (int fc = 0; fc < NC; fc++) acc[fr][fc] = (f32x4){0.f, 0.f, 0.f, 0.f};

  for (int kt = 0; kt < K; kt += 64) {
    __syncthreads();     // prior iteration's fragment reads complete
#pragma unroll
    for (int c = 0; c < 4; ++c) {          // A: 128 rows, hi + lo
      const size_t g = (size_t)(m0 + c * 32 + srow) * K + kt + sch * 8;
      __builtin_amdgcn_global_load_lds(
          (const __attribute__((address_space(1))) void*)(Ahi + g),
          (__attribute__((address_space(3))) void*)(Ah + c * 4096 + wv * 1024), 16, 0, 0);
      __builtin_amdgcn_global_load_lds(
          (const __attribute__((address_space(1))) void*)(Alo + g),
          (__attribute__((address_space(3))) void*)(Al + c * 4096 + wv * 1024), 16, 0, 0);
    }
#pragma unroll
    for (int c = 0; c < BN / 32; ++c) {    // B: BN rows, hi + lo
      const size_t g = (size_t)(n0 + c * 32 + srow) * K + kt + sch * 8;
      __builtin_amdgcn_global_load_lds(
          (const __attribute__((address_space(1))) void*)(Whi + g),
          (__attribute__((address_space(3))) void*)(Bh + c * 4096 + wv * 1024), 16, 0, 0);
      __builtin_amdgcn_global_load_lds(
          (const __attribute__((address_space(1))) void*)(Wlo + g),
          (__attribute__((address_space(3))) void*)(Bl + c * 4096 + wv * 1024), 16, 0, 0);
    }
    __syncthreads();     // compiler drains vmcnt before barrier

#pragma unroll
    for (int ks = 0; ks < 2; ++ks) {
      const int cc = ks * 4 + kq;
      bf16x8 afh[4], afl[4], bfh[NC], bfl[NC];
#pragma unroll
      for (int fr = 0; fr < 4; ++fr) {
        const int r = wr + fr * 16 + frow;
        const int off = r * 128 + (((cc ^ r) & 7) << 4);
        afh[fr] = *(const bf16x8*)(Ah + off);
        afl[fr] = *(const bf16x8*)(Al + off);
      }
#pragma unroll
      for (int fc = 0; fc < NC; ++fc) {
        const int r = wc + fc * 16 + frow;
        const int off = r * 128 + (((cc ^ r) & 7) << 4);
        bfh[fc] = *(const bf16x8*)(Bh + off);
        bfl[fc] = *(const bf16x8*)(Bl + off);
      }
#pragma unroll
      for (int fr = 0; fr < 4; ++fr)
#pragma unroll
        for (int fc = 0; fc < NC; ++fc) {
          acc[fr][fc] = __builtin_amdgcn_mfma_f32_16x16x32_bf16(afh[fr], bfh[fc], acc[fr][fc], 0, 0, 0);
          acc[fr][fc] = __builtin_amdgcn_mfma_f32_16x16x32_bf16(afh[fr], bfl[fc], acc[fr][fc], 0, 0, 0);
          acc[fr][fc] = __builtin_amdgcn_mfma_f32_16x16x32_bf16(afl[fr], bfh[fc], acc[fr][fc], 0, 0, 0);
        }
    }
  }

  const int rq = kq * 4;
#pragma unroll
  for (int fr = 0; fr < 4; fr++)
#pragma unroll
    for (int fc = 0; fc < NC; fc++)
#pragma unroll
      for (int j = 0; j < 4; j++) {
        const int row = m0 + wr + fr * 16 + rq + j;
        const int col = n0 + wc + fc * 16 + frow;
        float v = acc[fr][fc][j] + bias[col];
        if (RELU) v = fmaxf(v, 0.f);
        if constexpr (SPLIT_OUT) {
          const ushort hi = f2b(v);
          const int colc = swz_col(row, col);
          Chi[(size_t)row * N + colc] = hi;
          Clo[(size_t)row * N + colc] = f2b(v - b2f(hi));
        } else {
          C[(size_t)row * N + col] = v;
        }
      }
}

// ---------------------------------------------------------------------------
// pairs layout detection (parallel) + init
// ---------------------------------------------------------------------------
__global__ void init_flag_kernel(int* __restrict__ flag) { *flag = 0; }

__global__ __launch_bounds__(256) void detect_kernel(
    const unsigned long long* __restrict__ p64, int* __restrict__ flag)
{
  __shared__ int s;
  if (threadIdx.x == 0) s = 0;
  __syncthreads();
  int loc = 0;
  for (int i = blockIdx.x * 256 + threadIdx.x; i < NPAIR; i += 256 * 256)
    loc |= ((p64[i] >> 32) != 0ull) ? 1 : 0;
  if (loc) atomicOr(&s, 1);
  __syncthreads();
  if (threadIdx.x == 0 && s) atomicOr(flag, 1);
}

// ---------------------------------------------------------------------------
// final pair gather (fp32 out): [emb[pairs[:,0]], emb[pairs[:,1]]] ++ labels
// ---------------------------------------------------------------------------
__global__ __launch_bounds__(256) void gather_kernel(
    const float* __restrict__ emb, const unsigned long long* __restrict__ p64,
    const float* __restrict__ labels, const int* __restrict__ flagp,
    float* __restrict__ out)
{
  const int i = blockIdx.x * 256 + threadIdx.x;
  const int tot = 2 * NPAIR * OUTD;
  if (i < tot) {
    const int fl = *flagp;
    const int which = i / (NPAIR * OUTD);
    const int rem = i - which * (NPAIR * OUTD);
    const int p = rem >> 6, j = rem & 63;
    const int fi = p * 2 + which;
    int node;
    if (fl) {
      const unsigned long long w = p64[fi >> 1];
      node = (int)((fi & 1) ? (w >> 32) : (w & 0xffffffffull));
    } else {
      node = (int)p64[fi];
    }
    node &= (NTOT - 1);
    out[i] = emb[(size_t)node * OUTD + j];
  } else if (i < tot + NPAIR) {
    out[i] = labels[i - tot];
  }
}

extern "C" void kernel_launch(void* const* d_in, const int* in_sizes, int n_in,
                              void* d_out, int out_size, void* d_ws, size_t ws_size,
                              hipStream_t stream)
{
  const float* x      = (const float*)d_in[0];
  const unsigned long long* pairs = (const unsigned long long*)d_in[2];
  const float* labels = (const float*)d_in[3];
  const float* linW   = (const float*)d_in[4];
  const float* linb   = (const float*)d_in[5];
  const float* gatW   = (const float*)d_in[6];
  const float* attS   = (const float*)d_in[7];
  const float* attD   = (const float*)d_in[8];
  const float* gatb   = (const float*)d_in[9];
  const float* W1     = (const float*)d_in[10];
  const float* b1     = (const float*)d_in[11];
  const float* W2     = (const float*)d_in[12];
  const float* b2     = (const float*)d_in[13];
  const float* W3     = (const float*)d_in[14];
  const float* b3     = (const float*)d_in[15];

  float* ws = (float*)d_ws;
  const size_t NT = NTOT;
  // float-offset layout (overlays safe under serial stream ordering):
  float*  xl   = ws;                         // [0,128)   dead after attn
  ushort* e1hi = (ushort*)(ws);              // [0,256)   overlays xl
  ushort* e1lo = (ushort*)(ws + NT * 256);   // [256,512)
  ushort* ghi  = (ushort*)(ws + NT * 512);   // [512,576) dead after gemm1
  ushort* glo  = (ushort*)(ws + NT * 576);   // [576,640) dead after gemm1
  ushort* e2hi = (ushort*)(ws + NT * 512);   // [512,640) overlays ghi/glo
  ushort* e2lo = (ushort*)(ws + NT * 640);   // [640,768)
  float*  emb  = ws + NT * 768;              // [768,832)
  float*  asrc = ws + NT * 832;              // [832,833)
  float*  adst = ws + NT * 833;              // [833,834)
  ushort* wt1hi = (ushort*)(ws + NT * 834);
  ushort* wt1lo = wt1hi + 512 * 128;
  ushort* wt2hi = wt1lo + 512 * 128;
  ushort* wt2lo = wt2hi + 512 * 256;
  ushort* wt3hi = wt2lo + 512 * 256;
  ushort* wt3lo = wt3hi + 256 * 64;
  int*    flag  = (int*)(wt3lo + 256 * 64);

  init_flag_kernel<<<1, 1, 0, stream>>>(flag);
  detect_kernel<<<256, 256, 0, stream>>>(pairs, flag);
  convw_kernel<<<(128 * 512 + 255) / 256, 256, 0, stream>>>(W1, 128, 512, wt1hi, wt1lo);
  convw_kernel<<<(512 * 256 + 255) / 256, 256, 0, stream>>>(W2, 512, 256, wt2hi, wt2lo);
  convw_kernel<<<(256 * 64 + 255) / 256, 256, 0, stream>>>(W3, 256, 64, wt3hi, wt3lo);
  prep_kernel<<<NTOT / 16, 256, 0, stream>>>(x, linW, linb, gatW, attS, attD,
                                             xl, asrc, adst);
  attn_kernel<<<NTOT / 2, 256, 0, stream>>>(xl, asrc, adst, gatb, ghi, glo);

  constexpr int LDS_BN128 = 2 * (128 * 128) + 2 * (128 * 128);  // 65536
  constexpr int LDS_BN64  = 2 * (128 * 128) + 2 * (64 * 128);   // 49152
  mgemm_kernel<128, 512, 128, true,  true ><<<dim3(NTOT / 128, 4), 256, LDS_BN128, stream>>>(
      ghi, glo, wt1hi, wt1lo, b1, nullptr, e1hi, e1lo);
  mgemm_kernel<512, 256, 128, true,  true ><<<dim3(NTOT / 128, 2), 256, LDS_BN128, stream>>>(
      e1hi, e1lo, wt2hi, wt2lo, b2, nullptr, e2hi, e2lo);
  mgemm_kernel<256,  64,  64, false, false><<<dim3(NTOT / 128, 1), 256, LDS_BN64, stream>>>(
      e2hi, e2lo, wt3hi, wt3lo, b3, emb, nullptr, nullptr);
  const int total = 2 * NPAIR * OUTD + NPAIR;
  gather_kernel<<<(total + 255) / 256, 256, 0, stream>>>(emb, pairs, labels, flag, (float*)d_out);
}